// Round 8
// baseline (608.917 us; speedup 1.0000x reference)
//
#include <hip/hip_runtime.h>

#define Bdim 32
#define Ndim 577
#define Cdim 768
#define Hdim 12
#define Ddim 64
#define Mdim (Bdim*Ndim)   // 18464
#define VSTRIDE 640        // padded token stride for v^T (kt=9 reads stay in-bounds)
#define TSTRIDE 152        // v-transpose LDS tile token stride (304B rows, 16B-aligned)
#define QSCALE 0.18033688f // 0.125 * log2(e): attn uses exp2, so fold log2e into q
#define MGRP 19            // ceil(145/8) m-strip groups for XCD swizzle

typedef __attribute__((ext_vector_type(4))) float f32x4;
typedef __attribute__((ext_vector_type(8))) __bf16 bf16x8;
typedef __attribute__((ext_vector_type(4))) __bf16 bf16x4;

__device__ __forceinline__ void gl_lds16(const __bf16* g, __bf16* l) {
  __builtin_amdgcn_global_load_lds((const __attribute__((address_space(1))) void*)g,
                                   (__attribute__((address_space(3))) void*)l, 16, 0, 0);
}

// ---------------- fp32 -> bf16 convert (vectorized) --------------------------
__global__ __launch_bounds__(256) void f32_to_bf16(const float4* __restrict__ in,
                                                   bf16x4* __restrict__ out, int n4) {
  int i = blockIdx.x * 256 + threadIdx.x;
  if (i < n4) {
    float4 v = in[i];
    bf16x4 o = {(__bf16)v.x, (__bf16)v.y, (__bf16)v.z, (__bf16)v.w};
    out[i] = o;
  }
}

// ---- weight fp32 [768][Cc] -> fragment-major bf16 wf[n/16][k/8][16][8] ------
// wf element (n,k) = in[k][n]; a wave's MFMA B-frag load (16 n-rows x 8 k)
// becomes one contiguous, fully-coalesced 1KB global_load_dwordx4 per frag.
__global__ __launch_bounds__(256) void transpose_f32_wfrag(const float* __restrict__ in,
                                                           __bf16* __restrict__ out,
                                                           int Cc) {
  __shared__ float tile[64][65];      // [k-local][n-local]
  int bx = blockIdx.x * 64;           // n base
  int by = blockIdx.y * 64;           // k base (0..768)
  int tx = threadIdx.x & 63, ty = threadIdx.x >> 6;
  #pragma unroll
  for (int i = ty; i < 64; i += 4)
    tile[i][tx] = in[(size_t)(by + i) * Cc + bx + tx];
  __syncthreads();
  #pragma unroll
  for (int it = 0; it < 2; ++it) {
    int idx = it * 256 + threadIdx.x; // 0..511 = 64 n x 8 k-chunks
    int nl = idx & 63, kc = idx >> 6;
    bf16x8 o;
    #pragma unroll
    for (int j = 0; j < 8; ++j) o[j] = (__bf16)tile[kc * 8 + j][nl];
    int n = bx + nl, kk = by + kc * 8;
    *(bf16x8*)(out + ((size_t)(n >> 4) * 96 + (kk >> 3)) * 128 + (n & 15) * 8) = o;
  }
}

// ======== split-pipe GEMM core (r5, PROVEN): A via LDS, B direct from L2 =====
// B-frags load straight from L2-resident frag-major weights (coalesced 1KB/
// wave/frag) issued before A staging; both drain at one barrier. LDS traffic
// halved vs both-in-LDS. r6's T14 variant (reg-prefetch A) REGRESSED 17%:
// VGPR 84->96 cut occupancy 6->5 waves/SIMD and serialized the drain window --
// TLP, not pipelining, hides staging latency here (3rd falsification: r2 dbuf,
// r3 4-phase, r6 T14). Do not restructure this loop without new evidence.
__device__ __forceinline__ void gemm_split_core(const __bf16* __restrict__ A,
                                                const __bf16* __restrict__ WF,
                                                int m0, int n0,
                                                __bf16* As, f32x4 acc[4][4]) {
  const int t = threadIdx.x;
  const int lane = t & 63, w = t >> 6;
  const int quad = lane >> 4, l16 = lane & 15;
  const int wm = w >> 1, wn = w & 1;
  const int nb16 = (n0 >> 4) + wn * 4;

  for (int k0 = 0; k0 < 768; k0 += 64) {
    __syncthreads();                  // prev tile's LDS consumers done
    // B frags (both k32-halves) from global; no LDS dependency -> in flight
    // during staging, drained by the pre-barrier vmcnt(0) below.
    bf16x8 b[2][4];
    #pragma unroll
    for (int s = 0; s < 2; ++s)
      #pragma unroll
      for (int i = 0; i < 4; ++i)
        b[s][i] = *(const bf16x8*)(WF +
            ((size_t)(nb16 + i) * 96 + (k0 >> 3) + s * 4 + quad) * 128 + l16 * 8);
    // stage A tile: 4 x gl_lds16 / thread (h 0..1 halves x j 0..7 row-groups)
    #pragma unroll
    for (int e = 0; e < 4; ++e) {
      int h = e >> 1;
      int j = ((e & 1) << 2) | w;
      int row = j * 16 + (lane >> 2);
      int col = k0 + h * 32 + (lane & 3) * 8;
      int ar = m0 + row; if (ar > Mdim - 1) ar = Mdim - 1;   // M tail clamp
      gl_lds16(A + (size_t)ar * 768 + col, As + h * 4096 + j * 512 + lane * 8);
    }
    __syncthreads();                  // A staged + b[] resident
    #pragma unroll
    for (int s = 0; s < 2; ++s) {
      bf16x8 a[4];
      #pragma unroll
      for (int i = 0; i < 4; ++i)
        a[i] = *(const bf16x8*)(As + s * 4096 + (wm * 64 + i * 16 + l16) * 32 + quad * 8);
      #pragma unroll
      for (int mt = 0; mt < 4; ++mt)
        #pragma unroll
        for (int nt = 0; nt < 4; ++nt)
          acc[mt][nt] = __builtin_amdgcn_mfma_f32_16x16x32_bf16(a[mt], b[s][nt], acc[mt][nt], 0, 0, 0);
    }
  }
}

// XCD swizzle decode: all nb n-blocks of one m-strip land on one XCD
// (strip % 8 == linear % 8 under round-robin dispatch). Returns false for pads.
__device__ __forceinline__ bool xcd_decode(int lin, int nb, int mb, int& n, int& m) {
  int x8 = lin & 7;
  int rest = lin >> 3;
  n = rest % nb;
  int mg = rest / nb;
  m = mg * 8 + x8;
  return m < mb;
}

// ---------------- kernel 1a: Q/K GEMM + bias + RoPE (cols 0..1535) -----------
__global__ __launch_bounds__(256) void qk_kernel(const __bf16* __restrict__ x,
                                                 const __bf16* __restrict__ wf,
                                                 const float* __restrict__ b_qkv,
                                                 const float* __restrict__ rs,
                                                 const float* __restrict__ rc,
                                                 __bf16* __restrict__ q,
                                                 __bf16* __restrict__ k) {
  __shared__ __bf16 As[2 * 128 * 32];
  int nb, mbk;
  if (!xcd_decode(blockIdx.x, 12, 145, nb, mbk)) return;
  const int n0 = nb * 128, m0 = mbk * 128;

  f32x4 acc[4][4];
  const f32x4 fz = {0.f, 0.f, 0.f, 0.f};
  for (int i = 0; i < 4; ++i) for (int j = 0; j < 4; ++j) acc[i][j] = fz;
  gemm_split_core(x, wf, m0, n0, As, acc);

  const int lane = threadIdx.x & 63, w = threadIdx.x >> 6;
  const int quad = lane >> 4, l16 = lane & 15;
  const int wm = w >> 1, wn = w & 1;
  const int colbase = n0 + wn * 64;          // 64-aligned -> one (matrix, head)
  const int matrix = colbase / 768;          // 0=q 1=k
  const int head = (colbase % 768) / 64;

  #pragma unroll
  for (int mt = 0; mt < 4; ++mt) {
    int mbase = m0 + wm * 64 + mt * 16 + quad * 4;
    #pragma unroll
    for (int r = 0; r < 4; ++r) {
      int m = mbase + r;
      if (m >= Mdim) continue;
      int bb = m / 577, tok = m % 577;
      #pragma unroll
      for (int nt = 0; nt < 4; ++nt) {
        int d = nt * 16 + l16;
        float val = acc[mt][nt][r] + b_qkv[colbase + d];
        if (tok > 0) {
          float partner = acc[mt][nt ^ 2][r] + b_qkv[colbase + (d ^ 32)];
          float sn = rs[(size_t)(tok - 1) * 64 + d];
          float cs = rc[(size_t)(tok - 1) * 64 + d];
          float rot = (d < 32) ? -partner : partner;
          val = val * cs + rot * sn;
        }
        __bf16* dst;
        if (matrix == 0) { val *= QSCALE; dst = q; } else dst = k;
        dst[((size_t)(bb * 12 + head) * 577 + tok) * 64 + d] = (__bf16)val;
      }
    }
  }
}

// ---------------- kernel 1b: V GEMM + bias + LDS-transpose (cols 1536..2303) -
__global__ __launch_bounds__(256) void v_kernel(const __bf16* __restrict__ x,
                                                const __bf16* __restrict__ wf,
                                                const float* __restrict__ b_qkv,
                                                __bf16* __restrict__ vt) {
  __shared__ __bf16 As[2 * 128 * 32];
  __shared__ __bf16 Ts[64 * TSTRIDE];   // v-transpose half-tile [d-local][token]
  int nb, mbk;
  if (!xcd_decode(blockIdx.x, 6, 145, nb, mbk)) return;
  const int n0 = 1536 + nb * 128, m0 = mbk * 128;

  f32x4 acc[4][4];
  const f32x4 fz = {0.f, 0.f, 0.f, 0.f};
  for (int i = 0; i < 4; ++i) for (int j = 0; j < 4; ++j) acc[i][j] = fz;
  gemm_split_core(x, wf, m0, n0, As, acc);

  const int t = threadIdx.x;
  const int lane = t & 63, w = t >> 6;
  const int quad = lane >> 4, l16 = lane & 15;
  const int wm = w >> 1, wn = w & 1;
  const int colbase = n0 + wn * 64;

  #pragma unroll
  for (int h = 0; h < 2; ++h) {
    __syncthreads();
    if (wn == h) {
      #pragma unroll
      for (int mt = 0; mt < 4; ++mt) {
        int tokbase = wm * 64 + mt * 16 + quad * 4;
        #pragma unroll
        for (int r = 0; r < 4; ++r) {
          #pragma unroll
          for (int nt = 0; nt < 4; ++nt) {
            int dl = nt * 16 + l16;
            Ts[dl * TSTRIDE + tokbase + r] =
                (__bf16)(acc[mt][nt][r] + b_qkv[colbase + dl]);
          }
        }
      }
    }
    __syncthreads();
    int hh = (n0 + h * 64 - 1536) / 64;    // head for this half
    #pragma unroll
    for (int it = 0; it < 4; ++it) {
      int c = it * 256 + t;
      int dl = c >> 4, chunk = c & 15;
      bf16x8 vv = *(const bf16x8*)(Ts + dl * TSTRIDE + chunk * 8);
      #pragma unroll
      for (int j = 0; j < 8; ++j) {
        int m = m0 + chunk * 8 + j;
        if (m < Mdim) {
          int bb = m / 577, tok = m % 577;
          vt[((size_t)(bb * 12 + hh) * 64 + dl) * VSTRIDE + tok] = vv[j];
        }
      }
    }
  }
}

// ---------------- kernel 2: flash attention (barrier-free, r8) ---------------
// K/V per (b,h) = 145KB, L2-resident and shared by the 10 q-tile blocks on the
// same XCD (catalog Common-mistake #7: LDS-staging L2-fit data is overhead).
// Q-frags hoisted to regs (8 VGPR); K/V frags read DIRECTLY from global per
// MFMA -- per-lane 16B contiguous in both layouts, each 128B line reused 32x
// through L1 (8 frag-positions x 4 waves). qs/ks/vs LDS and ALL barriers are
// gone; only the wave-private ps strip remains (in-wave DS ordering suffices).
// Global addresses are byte-identical to what the old staging loop issued.
__global__ __launch_bounds__(256) void attn_kernel(const __bf16* __restrict__ q,
                                                   const __bf16* __restrict__ k,
                                                   const __bf16* __restrict__ vt,
                                                   __bf16* __restrict__ ao) {
  __shared__ __bf16 ps[64 * 72];   // P strip, padded stride 72 (16B-aligned rows)

  // XCD swizzle: all 10 q-tiles of one (b,h) on one XCD -> K/V L2-resident
  const int x8 = blockIdx.x & 7;
  const int rest = blockIdx.x >> 3;
  const int qt = rest % 10;
  const int bh = (rest / 10) * 8 + x8;

  const int t = threadIdx.x;
  const int lane = t & 63, w = t >> 6;
  const int quad = lane >> 4, l16 = lane & 15;

  const __bf16* qbase = q + (size_t)bh * 577 * 64;
  const __bf16* kbase = k + (size_t)bh * 577 * 64;
  const __bf16* vbase = vt + (size_t)bh * 64 * VSTRIDE;

  // Q-hoist: a-frag(s) element (l16, j) = Q[qt*64 + w*16 + l16][(s*4+quad)*8+j]
  // (rows >= 577 read in-workspace garbage; contained to discarded C rows)
  bf16x8 aq[2];
  #pragma unroll
  for (int s = 0; s < 2; ++s)
    aq[s] = *(const bf16x8*)(qbase + (size_t)(qt * 64 + w * 16 + l16) * 64 + (s * 4 + quad) * 8);

  f32x4 O[4]; const f32x4 fz = {0.f, 0.f, 0.f, 0.f};
  for (int i = 0; i < 4; ++i) O[i] = fz;
  float l_part[4] = {0.f, 0.f, 0.f, 0.f};

  for (int kt = 0; kt < 10; ++kt) {
    // S = q k^T  (q pre-scaled by 0.125*log2e); K frags straight from L1/L2:
    // b(s,nt) element (l16, j) = K[kt*64 + nt*16 + l16][(s*4+quad)*8 + j]
    f32x4 S[4]; for (int i = 0; i < 4; ++i) S[i] = fz;
    __builtin_amdgcn_s_setprio(1);
    #pragma unroll
    for (int s = 0; s < 2; ++s) {
      #pragma unroll
      for (int nt = 0; nt < 4; ++nt) {
        bf16x8 bk = *(const bf16x8*)(kbase +
            (size_t)(kt * 64 + nt * 16 + l16) * 64 + (s * 4 + quad) * 8);
        S[nt] = __builtin_amdgcn_mfma_f32_16x16x32_bf16(aq[s], bk, S[nt], 0, 0, 0);
      }
    }
    __builtin_amdgcn_s_setprio(0);

    // mask invalid keys (only kt==9: 577 = 9*64 + 1); exp2(-1e30) -> 0
    int kv_left = 577 - kt * 64;
    if (kv_left < 64) {
      #pragma unroll
      for (int nt = 0; nt < 4; ++nt) {
        int c = nt * 16 + l16;
        if (c >= kv_left) { S[nt][0] = -1e30f; S[nt][1] = -1e30f; S[nt][2] = -1e30f; S[nt][3] = -1e30f; }
      }
    }

    // softmax-lite: exp2, per-lane l accumulation, P -> LDS (A-layout via ps)
    #pragma unroll
    for (int r = 0; r < 4; ++r) {
      #pragma unroll
      for (int nt = 0; nt < 4; ++nt) {
        float e = exp2f(S[nt][r]);
        l_part[r] += e;
        ps[(size_t)(w * 16 + quad * 4 + r) * 72 + nt * 16 + l16] = (__bf16)e;
      }
    }

    // O += P @ V; V frags straight from L1/L2 (vt layout is d-major, token-
    // contiguous: per-lane 16B): b(s,dt) elem (l16,j) = V[(s*4+quad)*8+j][dt*16+l16]
    __builtin_amdgcn_s_setprio(1);
    #pragma unroll
    for (int s = 0; s < 2; ++s) {
      bf16x8 a = *(const bf16x8*)(ps + (size_t)(w * 16 + l16) * 72 + s * 32 + quad * 8);
      #pragma unroll
      for (int dt = 0; dt < 4; ++dt) {
        bf16x8 bv = *(const bf16x8*)(vbase +
            (size_t)(dt * 16 + l16) * VSTRIDE + kt * 64 + (s * 4 + quad) * 8);
        O[dt] = __builtin_amdgcn_mfma_f32_16x16x32_bf16(a, bv, O[dt], 0, 0, 0);
      }
    }
    __builtin_amdgcn_s_setprio(0);
  }

  // epilogue: reduce l across the 16 col-lanes, normalize, write ao[B*N, C]
  const int bb = bh / 12, hh = bh % 12;
  const int qrow0 = qt * 64 + w * 16 + quad * 4;
  #pragma unroll
  for (int r = 0; r < 4; ++r) {
    float l = l_part[r];
    l += __shfl_xor(l, 1); l += __shfl_xor(l, 2);
    l += __shfl_xor(l, 4); l += __shfl_xor(l, 8);
    int row = qrow0 + r;
    if (row < 577) {
      float inv = 1.f / l;
      size_t base = ((size_t)(bb * 577 + row)) * 768 + hh * 64;
      #pragma unroll
      for (int dt = 0; dt < 4; ++dt)
        ao[base + dt * 16 + l16] = (__bf16)(O[dt][r] * inv);
    }
  }
}

// ---------------- kernel 3: proj GEMM + bias -> fp32 out ---------------------
// Split core (r6's win, kept): w_proj (1.2MB) is L2-resident frag-major.
__global__ __launch_bounds__(256) void proj_kernel(const __bf16* __restrict__ ao,
                                                   const __bf16* __restrict__ wprojF,
                                                   const float* __restrict__ b_proj,
                                                   float* __restrict__ out) {
  __shared__ __bf16 As[2 * 128 * 32];
  int nb, mbk;
  if (!xcd_decode(blockIdx.x, 6, 145, nb, mbk)) return;
  const int n0 = nb * 128, m0 = mbk * 128;

  f32x4 acc[4][4];
  const f32x4 fz = {0.f, 0.f, 0.f, 0.f};
  for (int i = 0; i < 4; ++i) for (int j = 0; j < 4; ++j) acc[i][j] = fz;
  gemm_split_core(ao, wprojF, m0, n0, As, acc);

  const int lane = threadIdx.x & 63, w = threadIdx.x >> 6;
  const int quad = lane >> 4, l16 = lane & 15;
  const int wm = w >> 1, wn = w & 1;
  const int colbase = n0 + wn * 64;

  #pragma unroll
  for (int mt = 0; mt < 4; ++mt) {
    int mbase = m0 + wm * 64 + mt * 16 + quad * 4;
    #pragma unroll
    for (int r = 0; r < 4; ++r) {
      int m = mbase + r;
      if (m >= Mdim) continue;
      #pragma unroll
      for (int nt = 0; nt < 4; ++nt) {
        int c = colbase + nt * 16 + l16;
        out[(size_t)m * 768 + c] = acc[mt][nt][r] + b_proj[c];
      }
    }
  }
}

// ---------------- launch -----------------------------------------------------
extern "C" void kernel_launch(void* const* d_in, const int* in_sizes, int n_in,
                              void* d_out, int out_size, void* d_ws, size_t ws_size,
                              hipStream_t stream) {
  const float* x      = (const float*)d_in[0];
  const float* w_qkv  = (const float*)d_in[1];
  const float* b_qkv  = (const float*)d_in[2];
  const float* w_proj = (const float*)d_in[3];
  const float* b_proj = (const float*)d_in[4];
  const float* rsn    = (const float*)d_in[5];
  const float* rcs    = (const float*)d_in[6];
  float* out = (float*)d_out;

  // workspace layout (bf16 elements); ao aliases x_bf (x consumed before attn)
  constexpr size_t QK_E = (size_t)Bdim * Hdim * Ndim * Ddim;      // 14,180,352
  constexpr size_t VT_E = (size_t)Bdim * Hdim * Ddim * VSTRIDE;   // 15,728,640
  constexpr size_t AO_E = (size_t)Mdim * Cdim;                    // 14,180,352
  __bf16* q      = (__bf16*)d_ws;
  __bf16* k      = q + QK_E;
  __bf16* vt     = k + QK_E;
  __bf16* ao     = vt + VT_E;        // also holds x_bf before attn runs
  __bf16* xb     = ao;
  __bf16* wqkvF  = ao + AO_E;        // fragment-major qkv weights
  __bf16* wprojF = wqkvF + (size_t)2304 * 768;   // fragment-major proj weights
  // total: ~121 MB

  f32_to_bf16<<<13848, 256, 0, stream>>>((const float4*)x, (bf16x4*)xb,
                                         (int)(AO_E / 4));
  transpose_f32_wfrag<<<dim3(36, 12), 256, 0, stream>>>(w_qkv, wqkvF, 2304);
  transpose_f32_wfrag<<<dim3(12, 12), 256, 0, stream>>>(w_proj, wprojF, 768);
  qk_kernel<<<8 * MGRP * 12, 256, 0, stream>>>(xb, wqkvF, b_qkv, rsn, rcs, q, k);
  v_kernel<<<8 * MGRP * 6, 256, 0, stream>>>(xb, wqkvF, b_qkv, vt);
  attn_kernel<<<3840, 256, 0, stream>>>(q, k, vt, ao);
  proj_kernel<<<8 * MGRP * 6, 256, 0, stream>>>(ao, wprojF, b_proj, out);
}

// Round 9
// 418.895 us; speedup vs baseline: 1.4536x; 1.4536x over previous
//
#include <hip/hip_runtime.h>

#define Bdim 32
#define Ndim 577
#define Cdim 768
#define Hdim 12
#define Ddim 64
#define Mdim (Bdim*Ndim)   // 18464
#define VSTRIDE 640        // padded token stride for v^T (kt=9 staging stays in-bounds)
#define TSTRIDE 152        // v-transpose LDS tile token stride (304B rows, 16B-aligned)
#define QSCALE 0.18033688f // 0.125 * log2(e): attn uses exp2, so fold log2e into q
#define MGRP 19            // ceil(145/8) m-strip groups for XCD swizzle

typedef __attribute__((ext_vector_type(4))) float f32x4;
typedef __attribute__((ext_vector_type(8))) __bf16 bf16x8;
typedef __attribute__((ext_vector_type(4))) __bf16 bf16x4;

__device__ __forceinline__ void gl_lds16(const __bf16* g, __bf16* l) {
  __builtin_amdgcn_global_load_lds((const __attribute__((address_space(1))) void*)g,
                                   (__attribute__((address_space(3))) void*)l, 16, 0, 0);
}

// ---------------- fp32 -> bf16 convert (vectorized) --------------------------
__global__ __launch_bounds__(256) void f32_to_bf16(const float4* __restrict__ in,
                                                   bf16x4* __restrict__ out, int n4) {
  int i = blockIdx.x * 256 + threadIdx.x;
  if (i < n4) {
    float4 v = in[i];
    bf16x4 o = {(__bf16)v.x, (__bf16)v.y, (__bf16)v.z, (__bf16)v.w};
    out[i] = o;
  }
}

// ---- weight fp32 [768][Cc] -> fragment-major bf16 wf[n/16][k/8][16][8] ------
// wf element (n,k) = in[k][n]; a wave's MFMA B-frag load (16 n-rows x 8 k)
// becomes one contiguous, fully-coalesced 1KB global_load_dwordx4 per frag.
__global__ __launch_bounds__(256) void transpose_f32_wfrag(const float* __restrict__ in,
                                                           __bf16* __restrict__ out,
                                                           int Cc) {
  __shared__ float tile[64][65];      // [k-local][n-local]
  int bx = blockIdx.x * 64;           // n base
  int by = blockIdx.y * 64;           // k base (0..768)
  int tx = threadIdx.x & 63, ty = threadIdx.x >> 6;
  #pragma unroll
  for (int i = ty; i < 64; i += 4)
    tile[i][tx] = in[(size_t)(by + i) * Cc + bx + tx];
  __syncthreads();
  #pragma unroll
  for (int it = 0; it < 2; ++it) {
    int idx = it * 256 + threadIdx.x; // 0..511 = 64 n x 8 k-chunks
    int nl = idx & 63, kc = idx >> 6;
    bf16x8 o;
    #pragma unroll
    for (int j = 0; j < 8; ++j) o[j] = (__bf16)tile[kc * 8 + j][nl];
    int n = bx + nl, kk = by + kc * 8;
    *(bf16x8*)(out + ((size_t)(n >> 4) * 96 + (kk >> 3)) * 128 + (n & 15) * 8) = o;
  }
}

// ======== split-pipe GEMM core (r5, PROVEN): A via LDS, B direct from L2 =====
// Converged after 4 structural variants (2-barrier WINS vs r2 dbuf, r3 4-phase,
// r6 T14-reg): max occupancy + compiler-managed sync. FROZEN.
__device__ __forceinline__ void gemm_split_core(const __bf16* __restrict__ A,
                                                const __bf16* __restrict__ WF,
                                                int m0, int n0,
                                                __bf16* As, f32x4 acc[4][4]) {
  const int t = threadIdx.x;
  const int lane = t & 63, w = t >> 6;
  const int quad = lane >> 4, l16 = lane & 15;
  const int wm = w >> 1, wn = w & 1;
  const int nb16 = (n0 >> 4) + wn * 4;

  for (int k0 = 0; k0 < 768; k0 += 64) {
    __syncthreads();                  // prev tile's LDS consumers done
    bf16x8 b[2][4];
    #pragma unroll
    for (int s = 0; s < 2; ++s)
      #pragma unroll
      for (int i = 0; i < 4; ++i)
        b[s][i] = *(const bf16x8*)(WF +
            ((size_t)(nb16 + i) * 96 + (k0 >> 3) + s * 4 + quad) * 128 + l16 * 8);
    #pragma unroll
    for (int e = 0; e < 4; ++e) {
      int h = e >> 1;
      int j = ((e & 1) << 2) | w;
      int row = j * 16 + (lane >> 2);
      int col = k0 + h * 32 + (lane & 3) * 8;
      int ar = m0 + row; if (ar > Mdim - 1) ar = Mdim - 1;   // M tail clamp
      gl_lds16(A + (size_t)ar * 768 + col, As + h * 4096 + j * 512 + lane * 8);
    }
    __syncthreads();                  // A staged + b[] resident
    #pragma unroll
    for (int s = 0; s < 2; ++s) {
      bf16x8 a[4];
      #pragma unroll
      for (int i = 0; i < 4; ++i)
        a[i] = *(const bf16x8*)(As + s * 4096 + (wm * 64 + i * 16 + l16) * 32 + quad * 8);
      #pragma unroll
      for (int mt = 0; mt < 4; ++mt)
        #pragma unroll
        for (int nt = 0; nt < 4; ++nt)
          acc[mt][nt] = __builtin_amdgcn_mfma_f32_16x16x32_bf16(a[mt], b[s][nt], acc[mt][nt], 0, 0, 0);
    }
  }
}

// XCD swizzle decode: all nb n-blocks of one m-strip land on one XCD
// (strip % 8 == linear % 8 under round-robin dispatch). Returns false for pads.
__device__ __forceinline__ bool xcd_decode(int lin, int nb, int mb, int& n, int& m) {
  int x8 = lin & 7;
  int rest = lin >> 3;
  n = rest % nb;
  int mg = rest / nb;
  m = mg * 8 + x8;
  return m < mb;
}

// ---------------- kernel 1a: Q/K GEMM + bias + RoPE (cols 0..1535) -----------
__global__ __launch_bounds__(256) void qk_kernel(const __bf16* __restrict__ x,
                                                 const __bf16* __restrict__ wf,
                                                 const float* __restrict__ b_qkv,
                                                 const float* __restrict__ rs,
                                                 const float* __restrict__ rc,
                                                 __bf16* __restrict__ q,
                                                 __bf16* __restrict__ k) {
  __shared__ __bf16 As[2 * 128 * 32];
  int nb, mbk;
  if (!xcd_decode(blockIdx.x, 12, 145, nb, mbk)) return;
  const int n0 = nb * 128, m0 = mbk * 128;

  f32x4 acc[4][4];
  const f32x4 fz = {0.f, 0.f, 0.f, 0.f};
  for (int i = 0; i < 4; ++i) for (int j = 0; j < 4; ++j) acc[i][j] = fz;
  gemm_split_core(x, wf, m0, n0, As, acc);

  const int lane = threadIdx.x & 63, w = threadIdx.x >> 6;
  const int quad = lane >> 4, l16 = lane & 15;
  const int wm = w >> 1, wn = w & 1;
  const int colbase = n0 + wn * 64;          // 64-aligned -> one (matrix, head)
  const int matrix = colbase / 768;          // 0=q 1=k
  const int head = (colbase % 768) / 64;

  #pragma unroll
  for (int mt = 0; mt < 4; ++mt) {
    int mbase = m0 + wm * 64 + mt * 16 + quad * 4;
    #pragma unroll
    for (int r = 0; r < 4; ++r) {
      int m = mbase + r;
      if (m >= Mdim) continue;
      int bb = m / 577, tok = m % 577;
      #pragma unroll
      for (int nt = 0; nt < 4; ++nt) {
        int d = nt * 16 + l16;
        float val = acc[mt][nt][r] + b_qkv[colbase + d];
        if (tok > 0) {
          float partner = acc[mt][nt ^ 2][r] + b_qkv[colbase + (d ^ 32)];
          float sn = rs[(size_t)(tok - 1) * 64 + d];
          float cs = rc[(size_t)(tok - 1) * 64 + d];
          float rot = (d < 32) ? -partner : partner;
          val = val * cs + rot * sn;
        }
        __bf16* dst;
        if (matrix == 0) { val *= QSCALE; dst = q; } else dst = k;
        dst[((size_t)(bb * 12 + head) * 577 + tok) * 64 + d] = (__bf16)val;
      }
    }
  }
}

// ---------------- kernel 1b: V GEMM + bias + LDS-transpose (cols 1536..2303) -
__global__ __launch_bounds__(256) void v_kernel(const __bf16* __restrict__ x,
                                                const __bf16* __restrict__ wf,
                                                const float* __restrict__ b_qkv,
                                                __bf16* __restrict__ vt) {
  __shared__ __bf16 As[2 * 128 * 32];
  __shared__ __bf16 Ts[64 * TSTRIDE];   // v-transpose half-tile [d-local][token]
  int nb, mbk;
  if (!xcd_decode(blockIdx.x, 6, 145, nb, mbk)) return;
  const int n0 = 1536 + nb * 128, m0 = mbk * 128;

  f32x4 acc[4][4];
  const f32x4 fz = {0.f, 0.f, 0.f, 0.f};
  for (int i = 0; i < 4; ++i) for (int j = 0; j < 4; ++j) acc[i][j] = fz;
  gemm_split_core(x, wf, m0, n0, As, acc);

  const int t = threadIdx.x;
  const int lane = t & 63, w = t >> 6;
  const int quad = lane >> 4, l16 = lane & 15;
  const int wm = w >> 1, wn = w & 1;
  const int colbase = n0 + wn * 64;

  #pragma unroll
  for (int h = 0; h < 2; ++h) {
    __syncthreads();
    if (wn == h) {
      #pragma unroll
      for (int mt = 0; mt < 4; ++mt) {
        int tokbase = wm * 64 + mt * 16 + quad * 4;
        #pragma unroll
        for (int r = 0; r < 4; ++r) {
          #pragma unroll
          for (int nt = 0; nt < 4; ++nt) {
            int dl = nt * 16 + l16;
            Ts[dl * TSTRIDE + tokbase + r] =
                (__bf16)(acc[mt][nt][r] + b_qkv[colbase + dl]);
          }
        }
      }
    }
    __syncthreads();
    int hh = (n0 + h * 64 - 1536) / 64;    // head for this half
    #pragma unroll
    for (int it = 0; it < 4; ++it) {
      int c = it * 256 + t;
      int dl = c >> 4, chunk = c & 15;
      bf16x8 vv = *(const bf16x8*)(Ts + dl * TSTRIDE + chunk * 8);
      #pragma unroll
      for (int j = 0; j < 8; ++j) {
        int m = m0 + chunk * 8 + j;
        if (m < Mdim) {
          int bb = m / 577, tok = m % 577;
          vt[((size_t)(bb * 12 + hh) * 64 + dl) * VSTRIDE + tok] = vv[j];
        }
      }
    }
  }
}

// ---------------- kernel 2: flash attention (r9: 2 q-tiles/block) ------------
// r8 lesson: direct-from-global K/V per MFMA = uncoalesced gather + exposed
// latency chain (285us). LDS staging is load-bearing: it coalesces AND
// decouples. r9: keep r7's proven staging (reg-prefetch + ds_write, 2
// barriers/tile) but amortize it over TWO q-tiles per block (same (b,h) ->
// same K/V) and hold Q in registers (one-time read, drops qs LDS). Per staged
// tile: 32 MFMA instead of 16; K/V fetch + barrier count per unit work halved.
__global__ __launch_bounds__(256) void attn_kernel(const __bf16* __restrict__ q,
                                                   const __bf16* __restrict__ k,
                                                   const __bf16* __restrict__ vt,
                                                   __bf16* __restrict__ ao) {
  __shared__ __bf16 ks[4096];
  __shared__ __bf16 vs[4096];
  __shared__ __bf16 ps[64 * 72];   // P strip, padded stride 72 (16B-aligned rows)

  // XCD swizzle: all 5 q-pairs of one (b,h) on one XCD -> K/V L2-resident
  const int x8 = blockIdx.x & 7;
  const int rest = blockIdx.x >> 3;
  const int qp = rest % 5;                  // q-pair: tiles qp*2, qp*2+1
  const int bh = (rest / 5) * 8 + x8;

  const int t = threadIdx.x;
  const int lane = t & 63, w = t >> 6;
  const int quad = lane >> 4, l16 = lane & 15;

  const __bf16* qbase = q + (size_t)bh * 577 * 64;
  const __bf16* kbase = k + (size_t)bh * 577 * 64;
  const __bf16* vbase = vt + (size_t)bh * 64 * VSTRIDE;

  // Q-hoist to regs: aq[qi][s] elem (l16,j) = Q[qp*128+qi*64+w*16+l16][(s*4+quad)*8+j]
  // (rows >= 577 read in-workspace garbage; those C rows are discarded below)
  bf16x8 aq[2][2];
  #pragma unroll
  for (int qi = 0; qi < 2; ++qi)
    #pragma unroll
    for (int s = 0; s < 2; ++s)
      aq[qi][s] = *(const bf16x8*)(qbase +
          (size_t)(qp * 128 + qi * 64 + w * 16 + l16) * 64 + (s * 4 + quad) * 8);

  // K/V tile 0 -> registers (same (g -> d8,tok) mapping the LDS layout uses)
  bf16x8 kreg[2], vreg[2];
  #pragma unroll
  for (int p = 0; p < 2; ++p) {
    int g = p * 256 + t;
    kreg[p] = *(const bf16x8*)(kbase + (size_t)(g & 63) * 64 + (g >> 6) * 8);
    vreg[p] = *(const bf16x8*)(vbase + (size_t)(g & 63) * VSTRIDE + (g >> 6) * 8);
  }

  f32x4 O[2][4]; const f32x4 fz = {0.f, 0.f, 0.f, 0.f};
  for (int qi = 0; qi < 2; ++qi) for (int i = 0; i < 4; ++i) O[qi][i] = fz;
  float l_part[2][4] = {{0.f, 0.f, 0.f, 0.f}, {0.f, 0.f, 0.f, 0.f}};

  for (int kt = 0; kt < 10; ++kt) {
    __syncthreads();   // all readers of ks/vs (tile kt-1) done
    #pragma unroll
    for (int p = 0; p < 2; ++p) {
      int g = p * 256 + t;
      *(bf16x8*)(ks + (size_t)g * 8) = kreg[p];   // k: [d8][tok][8]
      *(bf16x8*)(vs + (size_t)g * 8) = vreg[p];   // v: [tok8][d][8]
    }
    __syncthreads();   // ds_writes visible to all waves

    // issue next tile's loads NOW; they complete under this tile's compute
    if (kt < 9) {
      #pragma unroll
      for (int p = 0; p < 2; ++p) {
        int g = p * 256 + t;
        kreg[p] = *(const bf16x8*)(kbase + (size_t)((kt + 1) * 64 + (g & 63)) * 64 + (g >> 6) * 8);
        vreg[p] = *(const bf16x8*)(vbase + (size_t)(g & 63) * VSTRIDE + (kt + 1) * 64 + (g >> 6) * 8);
      }
      __builtin_amdgcn_sched_barrier(0);   // pin load issue before compute
    }

    int kv_left = 577 - kt * 64;

    #pragma unroll
    for (int qi = 0; qi < 2; ++qi) {
      // S = q k^T  (q pre-scaled by 0.125*log2e)
      f32x4 S[4]; for (int i = 0; i < 4; ++i) S[i] = fz;
      __builtin_amdgcn_s_setprio(1);
      #pragma unroll
      for (int s = 0; s < 2; ++s) {
        #pragma unroll
        for (int nt = 0; nt < 4; ++nt) {
          bf16x8 b = *(const bf16x8*)(ks + (size_t)((s * 4 + quad) * 64 + nt * 16 + l16) * 8);
          S[nt] = __builtin_amdgcn_mfma_f32_16x16x32_bf16(aq[qi][s], b, S[nt], 0, 0, 0);
        }
      }
      __builtin_amdgcn_s_setprio(0);

      // mask invalid keys (only kt==9: 577 = 9*64 + 1); exp2(-1e30) -> 0
      if (kv_left < 64) {
        #pragma unroll
        for (int nt = 0; nt < 4; ++nt) {
          int c = nt * 16 + l16;
          if (c >= kv_left) { S[nt][0] = -1e30f; S[nt][1] = -1e30f; S[nt][2] = -1e30f; S[nt][3] = -1e30f; }
        }
      }

      // softmax-lite: exp2, per-lane l accumulation, P -> LDS (A-layout via ps)
      #pragma unroll
      for (int r = 0; r < 4; ++r) {
        #pragma unroll
        for (int nt = 0; nt < 4; ++nt) {
          float e = exp2f(S[nt][r]);
          l_part[qi][r] += e;
          ps[(size_t)(w * 16 + quad * 4 + r) * 72 + nt * 16 + l16] = (__bf16)e;
        }
      }

      // O += P @ V  (ps is wave-private; in-wave DS ordering covers w->r)
      __builtin_amdgcn_s_setprio(1);
      #pragma unroll
      for (int s = 0; s < 2; ++s) {
        bf16x8 a = *(const bf16x8*)(ps + (size_t)(w * 16 + l16) * 72 + s * 32 + quad * 8);
        #pragma unroll
        for (int dt = 0; dt < 4; ++dt) {
          bf16x8 b = *(const bf16x8*)(vs + (size_t)((s * 4 + quad) * 64 + dt * 16 + l16) * 8);
          O[qi][dt] = __builtin_amdgcn_mfma_f32_16x16x32_bf16(a, b, O[qi][dt], 0, 0, 0);
        }
      }
      __builtin_amdgcn_s_setprio(0);
    }
  }

  // epilogue: reduce l across the 16 col-lanes, normalize, write ao[B*N, C]
  const int bb = bh / 12, hh = bh % 12;
  #pragma unroll
  for (int qi = 0; qi < 2; ++qi) {
    const int qrow0 = qp * 128 + qi * 64 + w * 16 + quad * 4;
    #pragma unroll
    for (int r = 0; r < 4; ++r) {
      float l = l_part[qi][r];
      l += __shfl_xor(l, 1); l += __shfl_xor(l, 2);
      l += __shfl_xor(l, 4); l += __shfl_xor(l, 8);
      int row = qrow0 + r;
      if (row < 577) {
        float inv = 1.f / l;
        size_t base = ((size_t)(bb * 577 + row)) * 768 + hh * 64;
        #pragma unroll
        for (int dt = 0; dt < 4; ++dt)
          ao[base + dt * 16 + l16] = (__bf16)(O[qi][dt][r] * inv);
      }
    }
  }
}

// ---------------- kernel 3: proj GEMM + bias -> fp32 out ---------------------
// Split core (r6's win, kept): w_proj (1.2MB) is L2-resident frag-major.
__global__ __launch_bounds__(256) void proj_kernel(const __bf16* __restrict__ ao,
                                                   const __bf16* __restrict__ wprojF,
                                                   const float* __restrict__ b_proj,
                                                   float* __restrict__ out) {
  __shared__ __bf16 As[2 * 128 * 32];
  int nb, mbk;
  if (!xcd_decode(blockIdx.x, 6, 145, nb, mbk)) return;
  const int n0 = nb * 128, m0 = mbk * 128;

  f32x4 acc[4][4];
  const f32x4 fz = {0.f, 0.f, 0.f, 0.f};
  for (int i = 0; i < 4; ++i) for (int j = 0; j < 4; ++j) acc[i][j] = fz;
  gemm_split_core(ao, wprojF, m0, n0, As, acc);

  const int lane = threadIdx.x & 63, w = threadIdx.x >> 6;
  const int quad = lane >> 4, l16 = lane & 15;
  const int wm = w >> 1, wn = w & 1;
  const int colbase = n0 + wn * 64;

  #pragma unroll
  for (int mt = 0; mt < 4; ++mt) {
    int mbase = m0 + wm * 64 + mt * 16 + quad * 4;
    #pragma unroll
    for (int r = 0; r < 4; ++r) {
      int m = mbase + r;
      if (m >= Mdim) continue;
      #pragma unroll
      for (int nt = 0; nt < 4; ++nt) {
        int c = colbase + nt * 16 + l16;
        out[(size_t)m * 768 + c] = acc[mt][nt][r] + b_proj[c];
      }
    }
  }
}

// ---------------- launch -----------------------------------------------------
extern "C" void kernel_launch(void* const* d_in, const int* in_sizes, int n_in,
                              void* d_out, int out_size, void* d_ws, size_t ws_size,
                              hipStream_t stream) {
  const float* x      = (const float*)d_in[0];
  const float* w_qkv  = (const float*)d_in[1];
  const float* b_qkv  = (const float*)d_in[2];
  const float* w_proj = (const float*)d_in[3];
  const float* b_proj = (const float*)d_in[4];
  const float* rsn    = (const float*)d_in[5];
  const float* rcs    = (const float*)d_in[6];
  float* out = (float*)d_out;

  // workspace layout (bf16 elements); ao aliases x_bf (x consumed before attn)
  constexpr size_t QK_E = (size_t)Bdim * Hdim * Ndim * Ddim;      // 14,180,352
  constexpr size_t VT_E = (size_t)Bdim * Hdim * Ddim * VSTRIDE;   // 15,728,640
  constexpr size_t AO_E = (size_t)Mdim * Cdim;                    // 14,180,352
  __bf16* q      = (__bf16*)d_ws;
  __bf16* k      = q + QK_E;
  __bf16* vt     = k + QK_E;
  __bf16* ao     = vt + VT_E;        // also holds x_bf before attn runs
  __bf16* xb     = ao;
  __bf16* wqkvF  = ao + AO_E;        // fragment-major qkv weights
  __bf16* wprojF = wqkvF + (size_t)2304 * 768;   // fragment-major proj weights
  // total: ~121 MB

  f32_to_bf16<<<13848, 256, 0, stream>>>((const float4*)x, (bf16x4*)xb,
                                         (int)(AO_E / 4));
  transpose_f32_wfrag<<<dim3(36, 12), 256, 0, stream>>>(w_qkv, wqkvF, 2304);
  transpose_f32_wfrag<<<dim3(12, 12), 256, 0, stream>>>(w_proj, wprojF, 768);
  qk_kernel<<<8 * MGRP * 12, 256, 0, stream>>>(xb, wqkvF, b_qkv, rsn, rcs, q, k);
  v_kernel<<<8 * MGRP * 6, 256, 0, stream>>>(xb, wqkvF, b_qkv, vt);
  attn_kernel<<<1920, 256, 0, stream>>>(q, k, vt, ao);
  proj_kernel<<<8 * MGRP * 6, 256, 0, stream>>>(ao, wprojF, b_proj, out);
}